// Round 2
// baseline (720.432 us; speedup 1.0000x reference)
//
#include <hip/hip_runtime.h>
#include <math.h>

#define DMODEL 2048
#define NEXP   8
#define RANK   16
#define NPAIR  28   // unordered expert pairs C(8,2)
#define MAXT16 576  // >= sum ceil(n_p/16) <= 512+28
#define MAXT32 320  // >= sum ceil(n_p/32) <= 256+28

// ---------------- K1: router (logits -> top2 -> pair buckets) ----------------
__global__ __launch_bounds__(256, 2)
void router_kernel(const float* __restrict__ x,
                   const float* __restrict__ Wr,
                   const float* __restrict__ br,
                   float2* __restrict__ wparams,
                   int* __restrict__ cnt,
                   unsigned short* __restrict__ lists,
                   int nTok)
{
    __shared__ float wr_lds[DMODEL * NEXP];   // 64 KB
    const int tid = threadIdx.x;
    #pragma unroll
    for (int i = 0; i < 16; ++i) {
        const int f = (i*256 + tid)*4;
        *(float4*)&wr_lds[f] = *(const float4*)&Wr[f];
    }
    __syncthreads();

    const int s = tid >> 3;          // token slot 0..31
    const int j = tid & 7;           // d-lane 0..7
    const int tok = blockIdx.x*32 + s;
    const bool valid = tok < nTok;
    const float* xr = x + (size_t)(valid ? tok : 0) * DMODEL;

    float part[NEXP];
    #pragma unroll
    for (int e = 0; e < NEXP; ++e) part[e] = 0.f;

    for (int i = 0; i < 64; ++i) {
        const int d0 = (i*8 + j)*4;
        const float4 xv = *(const float4*)&xr[d0];
        #pragma unroll
        for (int q = 0; q < 4; ++q) {
            const float xq = (q==0)?xv.x:(q==1)?xv.y:(q==2)?xv.z:xv.w;
            const float4 w0 = *(const float4*)&wr_lds[(d0+q)*NEXP];
            const float4 w1 = *(const float4*)&wr_lds[(d0+q)*NEXP + 4];
            part[0] = fmaf(xq, w0.x, part[0]);
            part[1] = fmaf(xq, w0.y, part[1]);
            part[2] = fmaf(xq, w0.z, part[2]);
            part[3] = fmaf(xq, w0.w, part[3]);
            part[4] = fmaf(xq, w1.x, part[4]);
            part[5] = fmaf(xq, w1.y, part[5]);
            part[6] = fmaf(xq, w1.z, part[6]);
            part[7] = fmaf(xq, w1.w, part[7]);
        }
    }
    #pragma unroll
    for (int mres = 1; mres < 8; mres <<= 1) {
        #pragma unroll
        for (int e = 0; e < NEXP; ++e)
            part[e] += __shfl_xor(part[e], mres);
    }

    if (j == 0 && valid) {
        float lg[NEXP];
        #pragma unroll
        for (int e = 0; e < NEXP; ++e) lg[e] = part[e] + br[e];
        int b0 = 0; float v0 = lg[0];
        #pragma unroll
        for (int e = 1; e < NEXP; ++e) { if (lg[e] > v0) { v0 = lg[e]; b0 = e; } }
        int b1 = (b0 == 0) ? 1 : 0; float v1 = lg[b1];
        #pragma unroll
        for (int e = 0; e < NEXP; ++e) { if (e != b0 && lg[e] > v1) { v1 = lg[e]; b1 = e; } }
        const float t = expf(v1 - v0);
        const float wtop = 1.f / (1.f + t);
        const float wsec = t / (1.f + t);
        const int lo = (b0 < b1) ? b0 : b1;
        const int hi = (b0 < b1) ? b1 : b0;
        const float wlo = (b0 < b1) ? wtop : wsec;
        const float whi = (b0 < b1) ? wsec : wtop;
        wparams[tok] = make_float2(wlo, whi);
        const int pidx = lo*(NEXP-1) - (lo*(lo-1))/2 + (hi - lo - 1);
        const int pos = atomicAdd(&cnt[pidx], 1);
        lists[(size_t)pidx*nTok + pos] = (unsigned short)tok;
    }
}

// ---------------- K1.5: tile-offset prefix sums ----------------
__global__ void prefix_kernel(const int* __restrict__ cnt,
                              int* __restrict__ to16,
                              int* __restrict__ to32)
{
    if (threadIdx.x == 0) {
        int a16 = 0, a32 = 0;
        for (int p = 0; p < NPAIR; ++p) {
            to16[p] = a16; to32[p] = a32;
            a16 += (cnt[p] + 15) >> 4;
            a32 += (cnt[p] + 31) >> 5;
        }
        to16[NPAIR] = a16; to32[NPAIR] = a32;
    }
}

// ---------------- K2: down projection: hw[t][k][r] = w_k*relu(x.Wd[e_k]+bd) ----------------
__global__ __launch_bounds__(256, 3)
void down_kernel(const float* __restrict__ x,
                 const float* __restrict__ Wd,
                 const float* __restrict__ bd,
                 const float2* __restrict__ wparams,
                 const int* __restrict__ cnt,
                 const int* __restrict__ to16,
                 const unsigned short* __restrict__ lists,
                 float* __restrict__ hw,
                 int nTok)
{
    const int bx = blockIdx.x;
    if (bx >= to16[NPAIR]) return;
    int p = 0;
    while (to16[p+1] <= bx) ++p;
    const int tile = bx - to16[p];
    const int m = min(16, cnt[p] - tile*16);
    int lo = 0, rem = p;
    while (rem >= (NEXP-1-lo)) { rem -= (NEXP-1-lo); ++lo; }
    const int hi = lo + 1 + rem;

    __shared__ float x_lds[16][132];        // 8.4 KB, stride 132 (16B-aligned, conflict-free b32 reads)
    __shared__ float wd_lds[2][128][20];    // 20.5 KB, pad-20 rows
    __shared__ float w_lds[2][16];
    __shared__ int   tok_lds[16];

    const int tid = threadIdx.x;
    if (tid < 16) {
        const int idx = tile*16 + ((tid < m) ? tid : 0);
        const int t = lists[(size_t)p*nTok + idx];
        tok_lds[tid] = t;
        const float2 w = wparams[t];
        w_lds[0][tid] = (tid < m) ? w.x : 0.f;
        w_lds[1][tid] = (tid < m) ? w.y : 0.f;
    }
    __syncthreads();

    const int dg = tid & 31;        // 32 d-lanes
    const int kq = tid >> 5;
    const int k  = kq >> 2;         // expert slot
    const int tq = kq & 3;          // token quad
    const int e  = k ? hi : lo;

    const int sA = tid >> 4;        // staging row 0..15
    const int bA = tid & 15;        // staging col-group (8 floats)
    const size_t xbase = (size_t)tok_lds[sA]*DMODEL + bA*8;

    float acc[4][16];
    #pragma unroll
    for (int i = 0; i < 4; ++i)
        #pragma unroll
        for (int r = 0; r < 16; ++r) acc[i][r] = 0.f;

    for (int c = 0; c < 16; ++c) {
        // issue global loads first (hide latency behind the barrier)
        const float4 xa = *(const float4*)&x[xbase + c*128];
        const float4 xb = *(const float4*)&x[xbase + c*128 + 4];
        float4 wv[4];
        #pragma unroll
        for (int o = 0; o < 4; ++o) {
            const int f  = tid*16 + o*4;     // 0..4095
            const int kk = f >> 11;
            const int f2 = f & 2047;
            const int es = kk ? hi : lo;
            wv[o] = *(const float4*)&Wd[(size_t)es*(DMODEL*RANK) + (size_t)c*2048 + f2];
        }
        __syncthreads();   // previous chunk's consumers done
        *(float4*)&x_lds[sA][bA*8]     = xa;
        *(float4*)&x_lds[sA][bA*8 + 4] = xb;
        #pragma unroll
        for (int o = 0; o < 4; ++o) {
            const int f  = tid*16 + o*4;
            const int kk = f >> 11;
            const int f2 = f & 2047;
            *(float4*)&wd_lds[kk][f2 >> 4][f2 & 15] = wv[o];
        }
        __syncthreads();
        #pragma unroll
        for (int j = 0; j < 4; ++j) {
            const int d = j*32 + dg;
            const float4 wa = *(const float4*)&wd_lds[k][d][0];
            const float4 wb = *(const float4*)&wd_lds[k][d][4];
            const float4 wc = *(const float4*)&wd_lds[k][d][8];
            const float4 we = *(const float4*)&wd_lds[k][d][12];
            #pragma unroll
            for (int i = 0; i < 4; ++i) {
                const float xv = x_lds[tq*4 + i][d];
                acc[i][0]  = fmaf(xv, wa.x, acc[i][0]);
                acc[i][1]  = fmaf(xv, wa.y, acc[i][1]);
                acc[i][2]  = fmaf(xv, wa.z, acc[i][2]);
                acc[i][3]  = fmaf(xv, wa.w, acc[i][3]);
                acc[i][4]  = fmaf(xv, wb.x, acc[i][4]);
                acc[i][5]  = fmaf(xv, wb.y, acc[i][5]);
                acc[i][6]  = fmaf(xv, wb.z, acc[i][6]);
                acc[i][7]  = fmaf(xv, wb.w, acc[i][7]);
                acc[i][8]  = fmaf(xv, wc.x, acc[i][8]);
                acc[i][9]  = fmaf(xv, wc.y, acc[i][9]);
                acc[i][10] = fmaf(xv, wc.z, acc[i][10]);
                acc[i][11] = fmaf(xv, wc.w, acc[i][11]);
                acc[i][12] = fmaf(xv, we.x, acc[i][12]);
                acc[i][13] = fmaf(xv, we.y, acc[i][13]);
                acc[i][14] = fmaf(xv, we.z, acc[i][14]);
                acc[i][15] = fmaf(xv, we.w, acc[i][15]);
            }
        }
    }

    // butterfly reduce across the 32 d-lanes
    #pragma unroll
    for (int mm = 1; mm <= 16; mm <<= 1)
        #pragma unroll
        for (int i = 0; i < 4; ++i)
            #pragma unroll
            for (int r = 0; r < 16; ++r)
                acc[i][r] += __shfl_xor(acc[i][r], mm);

    if (dg == 0) {
        #pragma unroll
        for (int i = 0; i < 4; ++i) {
            const int slot = tq*4 + i;
            if (slot < m) {
                const int t = tok_lds[slot];
                const float w = w_lds[k][slot];
                float4 h0, h1, h2, h3;
                h0.x = fmaxf(acc[i][0]  + bd[e*RANK+0],  0.f) * w;
                h0.y = fmaxf(acc[i][1]  + bd[e*RANK+1],  0.f) * w;
                h0.z = fmaxf(acc[i][2]  + bd[e*RANK+2],  0.f) * w;
                h0.w = fmaxf(acc[i][3]  + bd[e*RANK+3],  0.f) * w;
                h1.x = fmaxf(acc[i][4]  + bd[e*RANK+4],  0.f) * w;
                h1.y = fmaxf(acc[i][5]  + bd[e*RANK+5],  0.f) * w;
                h1.z = fmaxf(acc[i][6]  + bd[e*RANK+6],  0.f) * w;
                h1.w = fmaxf(acc[i][7]  + bd[e*RANK+7],  0.f) * w;
                h2.x = fmaxf(acc[i][8]  + bd[e*RANK+8],  0.f) * w;
                h2.y = fmaxf(acc[i][9]  + bd[e*RANK+9],  0.f) * w;
                h2.z = fmaxf(acc[i][10] + bd[e*RANK+10], 0.f) * w;
                h2.w = fmaxf(acc[i][11] + bd[e*RANK+11], 0.f) * w;
                h3.x = fmaxf(acc[i][12] + bd[e*RANK+12], 0.f) * w;
                h3.y = fmaxf(acc[i][13] + bd[e*RANK+13], 0.f) * w;
                h3.z = fmaxf(acc[i][14] + bd[e*RANK+14], 0.f) * w;
                h3.w = fmaxf(acc[i][15] + bd[e*RANK+15], 0.f) * w;
                float* hp = &hw[(size_t)t*32 + k*16];
                *(float4*)&hp[0]  = h0;
                *(float4*)&hp[4]  = h1;
                *(float4*)&hp[8]  = h2;
                *(float4*)&hp[12] = h3;
            }
        }
    }
}

// ---------------- K3: up projection: out[t][d] = sum_kr hw[t][kr]*Wu + w.bu ----------------
__global__ __launch_bounds__(256, 4)
void up_kernel(const float* __restrict__ Wu,
               const float* __restrict__ bu,
               const float2* __restrict__ wparams,
               const int* __restrict__ cnt,
               const int* __restrict__ to32,
               const unsigned short* __restrict__ lists,
               const float* __restrict__ hw,
               float* __restrict__ out,
               int nTok)
{
    const int bx = blockIdx.x;
    if (bx >= to32[NPAIR]) return;
    int p = 0;
    while (to32[p+1] <= bx) ++p;
    const int tile = bx - to32[p];
    const int m = min(32, cnt[p] - tile*32);
    int lo = 0, rem = p;
    while (rem >= (NEXP-1-lo)) { rem -= (NEXP-1-lo); ++lo; }
    const int hi = lo + 1 + rem;
    const int cc = blockIdx.y;        // d-chunk of 256

    __shared__ float wu_lds[2][16][256];   // 32 KB
    __shared__ float h_lds[32][36];        // 4.6 KB (stride 36: 16B aligned)
    __shared__ float w2_lds[2][32];
    __shared__ int   tok_lds[32];

    const int tid = threadIdx.x;

    // stage Wu chunk (independent of token list) -> regs
    float4 wv[8];
    #pragma unroll
    for (int i = 0; i < 8; ++i) {
        const int f  = i*1024 + tid*4;   // 0..8191
        const int kk = f >> 12;
        const int rr = (f >> 8) & 15;
        const int dd = f & 255;
        const int es = kk ? hi : lo;
        wv[i] = *(const float4*)&Wu[(size_t)es*(RANK*DMODEL) + (size_t)rr*DMODEL + cc*256 + dd];
    }

    if (tid < 32) {
        const int idx = tile*32 + ((tid < m) ? tid : 0);
        const int t = lists[(size_t)p*nTok + idx];
        tok_lds[tid] = t;
        const float2 w = wparams[t];
        w2_lds[0][tid] = (tid < m) ? w.x : 0.f;
        w2_lds[1][tid] = (tid < m) ? w.y : 0.f;
    }
    __syncthreads();

    {   // gather h' (1 float4 per thread)
        const int tk = tid >> 3, o = (tid & 7) * 4;
        const float4 hv = *(const float4*)&hw[(size_t)tok_lds[tk]*32 + o];
        *(float4*)&h_lds[tk][o] = hv;
    }
    #pragma unroll
    for (int i = 0; i < 8; ++i) {
        const int f  = i*1024 + tid*4;
        const int kk = f >> 12;
        const int rr = (f >> 8) & 15;
        const int dd = f & 255;
        *(float4*)&wu_lds[kk][rr][dd] = wv[i];
    }
    __syncthreads();

    const int dg = tid & 31;    // 32 d-groups (4 floats each, two halves)
    const int tq = tid >> 5;    // 8 token quads
    float4 a0[4], a1[4];
    #pragma unroll
    for (int i = 0; i < 4; ++i) { a0[i] = make_float4(0,0,0,0); a1[i] = make_float4(0,0,0,0); }

    #pragma unroll
    for (int kr = 0; kr < 32; ++kr) {
        const int kk = kr >> 4, rr = kr & 15;
        const float4 u0 = *(const float4*)&wu_lds[kk][rr][dg*4];
        const float4 u1 = *(const float4*)&wu_lds[kk][rr][128 + dg*4];
        #pragma unroll
        for (int i = 0; i < 4; ++i) {
            const float hv = h_lds[tq*4 + i][kr];
            a0[i].x = fmaf(hv, u0.x, a0[i].x);
            a0[i].y = fmaf(hv, u0.y, a0[i].y);
            a0[i].z = fmaf(hv, u0.z, a0[i].z);
            a0[i].w = fmaf(hv, u0.w, a0[i].w);
            a1[i].x = fmaf(hv, u1.x, a1[i].x);
            a1[i].y = fmaf(hv, u1.y, a1[i].y);
            a1[i].z = fmaf(hv, u1.z, a1[i].z);
            a1[i].w = fmaf(hv, u1.w, a1[i].w);
        }
    }

    const float4 bl0 = *(const float4*)&bu[(size_t)lo*DMODEL + cc*256 + dg*4];
    const float4 bl1 = *(const float4*)&bu[(size_t)lo*DMODEL + cc*256 + 128 + dg*4];
    const float4 bh0 = *(const float4*)&bu[(size_t)hi*DMODEL + cc*256 + dg*4];
    const float4 bh1 = *(const float4*)&bu[(size_t)hi*DMODEL + cc*256 + 128 + dg*4];

    #pragma unroll
    for (int i = 0; i < 4; ++i) {
        const int slot = tq*4 + i;
        if (slot < m) {
            const int t = tok_lds[slot];
            const float wl = w2_lds[0][slot];
            const float wh = w2_lds[1][slot];
            float4 o0 = a0[i], o1 = a1[i];
            o0.x += wl*bl0.x + wh*bh0.x;  o0.y += wl*bl0.y + wh*bh0.y;
            o0.z += wl*bl0.z + wh*bh0.z;  o0.w += wl*bl0.w + wh*bh0.w;
            o1.x += wl*bl1.x + wh*bh1.x;  o1.y += wl*bl1.y + wh*bh1.y;
            o1.z += wl*bl1.z + wh*bh1.z;  o1.w += wl*bl1.w + wh*bh1.w;
            float* op = &out[(size_t)t*DMODEL + cc*256];
            *(float4*)&op[dg*4]       = o0;
            *(float4*)&op[128 + dg*4] = o1;
        }
    }
}

extern "C" void kernel_launch(void* const* d_in, const int* in_sizes, int n_in,
                              void* d_out, int out_size, void* d_ws, size_t ws_size,
                              hipStream_t stream)
{
    (void)n_in; (void)out_size; (void)ws_size;
    const float* x  = (const float*)d_in[0];
    const float* Wr = (const float*)d_in[1];
    const float* br = (const float*)d_in[2];
    const float* Wd = (const float*)d_in[3];
    const float* bd = (const float*)d_in[4];
    const float* Wu = (const float*)d_in[5];
    const float* bu = (const float*)d_in[6];
    float* out = (float*)d_out;
    const int nTok = in_sizes[0] / DMODEL;   // 8192

    // ws layout:
    // [0,112)    cnt (28 ints)
    // [128,244)  to16 (29 ints)
    // [256,372)  to32 (29 ints)
    // [512, +8*nTok)          wparams
    // [.., +2*NPAIR*nTok)     lists
    // [aligned 256, +128*nTok) hw
    char* base = (char*)d_ws;
    int* cnt  = (int*)(base);
    int* to16 = (int*)(base + 128);
    int* to32 = (int*)(base + 256);
    float2* wparams = (float2*)(base + 512);
    size_t off = 512 + (size_t)nTok*sizeof(float2);
    unsigned short* lists = (unsigned short*)(base + off);
    off += (size_t)NPAIR*nTok*sizeof(unsigned short);
    off = (off + 255) & ~(size_t)255;
    float* hw = (float*)(base + off);

    hipMemsetAsync(d_ws, 0, 512, stream);
    const int ntiles = (nTok + 31)/32;
    router_kernel<<<ntiles, 256, 0, stream>>>(x, Wr, br, wparams, cnt, lists, nTok);
    prefix_kernel<<<1, 64, 0, stream>>>(cnt, to16, to32);
    down_kernel<<<MAXT16, 256, 0, stream>>>(x, Wd, bd, wparams, cnt, to16, lists, hw, nTok);
    dim3 gup(MAXT32, 8);
    up_kernel<<<gup, 256, 0, stream>>>(Wu, bu, wparams, cnt, to32, lists, hw, out, nTok);
}

// Round 3
// 111.574 us; speedup vs baseline: 6.4570x; 6.4570x over previous
//
#include <hip/hip_runtime.h>
#include <math.h>

#define DMODEL 2048
#define NEXP   8
#define RANK   16
#define NPAIR  28   // unordered expert pairs C(8,2)
#define MAXT16 576  // >= sum ceil(n_p/16) <= 512+28
#define MAXT32 320  // >= sum ceil(n_p/32) <= 256+28

// ---------------- K1: router (logits -> top2 -> pair buckets) ----------------
__global__ __launch_bounds__(256, 2)
void router_kernel(const float* __restrict__ x,
                   const float* __restrict__ Wr,
                   const float* __restrict__ br,
                   float2* __restrict__ wparams,
                   int* __restrict__ cnt,
                   unsigned short* __restrict__ lists,
                   int nTok)
{
    __shared__ float wr_lds[DMODEL * NEXP];   // 64 KB
    const int tid = threadIdx.x;
    #pragma unroll
    for (int i = 0; i < 16; ++i) {
        const int f = (i*256 + tid)*4;
        *(float4*)&wr_lds[f] = *(const float4*)&Wr[f];
    }
    __syncthreads();

    const int s = tid >> 3;          // token slot 0..31
    const int j = tid & 7;           // d-lane 0..7
    const int tok = blockIdx.x*32 + s;
    const bool valid = tok < nTok;
    const float* xr = x + (size_t)(valid ? tok : 0) * DMODEL;

    float part[NEXP];
    #pragma unroll
    for (int e = 0; e < NEXP; ++e) part[e] = 0.f;

    for (int i = 0; i < 64; ++i) {
        const int d0 = (i*8 + j)*4;
        const float4 xv = *(const float4*)&xr[d0];
        #pragma unroll
        for (int q = 0; q < 4; ++q) {
            const float xq = (q==0)?xv.x:(q==1)?xv.y:(q==2)?xv.z:xv.w;
            const float4 w0 = *(const float4*)&wr_lds[(d0+q)*NEXP];
            const float4 w1 = *(const float4*)&wr_lds[(d0+q)*NEXP + 4];
            part[0] = fmaf(xq, w0.x, part[0]);
            part[1] = fmaf(xq, w0.y, part[1]);
            part[2] = fmaf(xq, w0.z, part[2]);
            part[3] = fmaf(xq, w0.w, part[3]);
            part[4] = fmaf(xq, w1.x, part[4]);
            part[5] = fmaf(xq, w1.y, part[5]);
            part[6] = fmaf(xq, w1.z, part[6]);
            part[7] = fmaf(xq, w1.w, part[7]);
        }
    }
    #pragma unroll
    for (int mres = 1; mres < 8; mres <<= 1) {
        #pragma unroll
        for (int e = 0; e < NEXP; ++e)
            part[e] += __shfl_xor(part[e], mres);
    }

    if (j == 0 && valid) {
        float lg[NEXP];
        #pragma unroll
        for (int e = 0; e < NEXP; ++e) lg[e] = part[e] + br[e];
        int b0 = 0; float v0 = lg[0];
        #pragma unroll
        for (int e = 1; e < NEXP; ++e) { if (lg[e] > v0) { v0 = lg[e]; b0 = e; } }
        int b1 = (b0 == 0) ? 1 : 0; float v1 = lg[b1];
        #pragma unroll
        for (int e = 0; e < NEXP; ++e) { if (e != b0 && lg[e] > v1) { v1 = lg[e]; b1 = e; } }
        const float t = expf(v1 - v0);
        const float wtop = 1.f / (1.f + t);
        const float wsec = t / (1.f + t);
        const int lo = (b0 < b1) ? b0 : b1;
        const int hi = (b0 < b1) ? b1 : b0;
        const float wlo = (b0 < b1) ? wtop : wsec;
        const float whi = (b0 < b1) ? wsec : wtop;
        wparams[tok] = make_float2(wlo, whi);
        const int pidx = lo*(NEXP-1) - (lo*(lo-1))/2 + (hi - lo - 1);
        const int pos = atomicAdd(&cnt[pidx], 1);
        lists[(size_t)pidx*nTok + pos] = (unsigned short)tok;
    }
}

// ---------------- K1.5: tile-offset prefix sums ----------------
__global__ void prefix_kernel(const int* __restrict__ cnt,
                              int* __restrict__ to16,
                              int* __restrict__ to32)
{
    if (threadIdx.x == 0) {
        int a16 = 0, a32 = 0;
        for (int p = 0; p < NPAIR; ++p) {
            to16[p] = a16; to32[p] = a32;
            a16 += (cnt[p] + 15) >> 4;
            a32 += (cnt[p] + 31) >> 5;
        }
        to16[NPAIR] = a16; to32[NPAIR] = a32;
    }
}

// ---------------- K2: down projection: hw[t][k][r] = w_k*relu(x.Wd[e_k]+bd) ----------------
__global__ __launch_bounds__(256, 2)
void down_kernel(const float* __restrict__ x,
                 const float* __restrict__ Wd,
                 const float* __restrict__ bd,
                 const float2* __restrict__ wparams,
                 const int* __restrict__ cnt,
                 const int* __restrict__ to16,
                 const unsigned short* __restrict__ lists,
                 float* __restrict__ hw,
                 int nTok)
{
    const int bx = blockIdx.x;
    if (bx >= to16[NPAIR]) return;
    int p = 0;
    while (to16[p+1] <= bx) ++p;
    const int tile = bx - to16[p];
    const int m = min(16, cnt[p] - tile*16);
    int lo = 0, rem = p;
    while (rem >= (NEXP-1-lo)) { rem -= (NEXP-1-lo); ++lo; }
    const int hi = lo + 1 + rem;

    __shared__ float x_lds[16][132];        // 8.4 KB (stride 132: 16B aligned)
    __shared__ float wd_lds[2][128][20];    // 20.5 KB, pad-20 rows
    __shared__ float w_lds[2][16];
    __shared__ int   tok_lds[16];

    const int tid = threadIdx.x;
    if (tid < 16) {
        const int idx = tile*16 + ((tid < m) ? tid : 0);
        const int t = lists[(size_t)p*nTok + idx];
        tok_lds[tid] = t;
        const float2 w = wparams[t];
        w_lds[0][tid] = (tid < m) ? w.x : 0.f;
        w_lds[1][tid] = (tid < m) ? w.y : 0.f;
    }
    __syncthreads();

    const int dg = tid & 31;        // 32 d-lanes
    const int kq = tid >> 5;
    const int k  = kq >> 2;         // expert slot
    const int tq = kq & 3;          // token quad
    const int e  = k ? hi : lo;

    const int sA = tid >> 4;        // staging row 0..15
    const int bA = tid & 15;        // staging col-group (8 floats)
    const size_t xbase = (size_t)tok_lds[sA]*DMODEL + bA*8;

    float acc[4][16];
    #pragma unroll
    for (int i = 0; i < 4; ++i)
        #pragma unroll
        for (int r = 0; r < 16; ++r) acc[i][r] = 0.f;

    for (int c = 0; c < 16; ++c) {
        if (c) __syncthreads();    // previous chunk's consumers done
        // stage x chunk [16 tok][128 d] -- direct global->LDS, no reg prefetch
        *(float4*)&x_lds[sA][bA*8]     = *(const float4*)&x[xbase + c*128];
        *(float4*)&x_lds[sA][bA*8 + 4] = *(const float4*)&x[xbase + c*128 + 4];
        // stage Wd chunk for both experts
        #pragma unroll
        for (int o = 0; o < 4; ++o) {
            const int f  = tid*16 + o*4;     // 0..4095
            const int kk = f >> 11;
            const int f2 = f & 2047;
            const int es = kk ? hi : lo;
            *(float4*)&wd_lds[kk][f2 >> 4][f2 & 15] =
                *(const float4*)&Wd[(size_t)es*(DMODEL*RANK) + (size_t)c*2048 + f2];
        }
        __syncthreads();
        #pragma unroll
        for (int j = 0; j < 4; ++j) {
            const int d = j*32 + dg;
            const float4 wa = *(const float4*)&wd_lds[k][d][0];
            const float4 wb = *(const float4*)&wd_lds[k][d][4];
            const float4 wc = *(const float4*)&wd_lds[k][d][8];
            const float4 we = *(const float4*)&wd_lds[k][d][12];
            #pragma unroll
            for (int i = 0; i < 4; ++i) {
                const float xv = x_lds[tq*4 + i][d];
                acc[i][0]  = fmaf(xv, wa.x, acc[i][0]);
                acc[i][1]  = fmaf(xv, wa.y, acc[i][1]);
                acc[i][2]  = fmaf(xv, wa.z, acc[i][2]);
                acc[i][3]  = fmaf(xv, wa.w, acc[i][3]);
                acc[i][4]  = fmaf(xv, wb.x, acc[i][4]);
                acc[i][5]  = fmaf(xv, wb.y, acc[i][5]);
                acc[i][6]  = fmaf(xv, wb.z, acc[i][6]);
                acc[i][7]  = fmaf(xv, wb.w, acc[i][7]);
                acc[i][8]  = fmaf(xv, wc.x, acc[i][8]);
                acc[i][9]  = fmaf(xv, wc.y, acc[i][9]);
                acc[i][10] = fmaf(xv, wc.z, acc[i][10]);
                acc[i][11] = fmaf(xv, wc.w, acc[i][11]);
                acc[i][12] = fmaf(xv, we.x, acc[i][12]);
                acc[i][13] = fmaf(xv, we.y, acc[i][13]);
                acc[i][14] = fmaf(xv, we.z, acc[i][14]);
                acc[i][15] = fmaf(xv, we.w, acc[i][15]);
            }
        }
    }

    // butterfly reduce across the 32 d-lanes
    #pragma unroll
    for (int mm = 1; mm <= 16; mm <<= 1)
        #pragma unroll
        for (int i = 0; i < 4; ++i)
            #pragma unroll
            for (int r = 0; r < 16; ++r)
                acc[i][r] += __shfl_xor(acc[i][r], mm);

    if (dg == 0) {
        #pragma unroll
        for (int i = 0; i < 4; ++i) {
            const int slot = tq*4 + i;
            if (slot < m) {
                const int t = tok_lds[slot];
                const float w = w_lds[k][slot];
                float4 h0, h1, h2, h3;
                h0.x = fmaxf(acc[i][0]  + bd[e*RANK+0],  0.f) * w;
                h0.y = fmaxf(acc[i][1]  + bd[e*RANK+1],  0.f) * w;
                h0.z = fmaxf(acc[i][2]  + bd[e*RANK+2],  0.f) * w;
                h0.w = fmaxf(acc[i][3]  + bd[e*RANK+3],  0.f) * w;
                h1.x = fmaxf(acc[i][4]  + bd[e*RANK+4],  0.f) * w;
                h1.y = fmaxf(acc[i][5]  + bd[e*RANK+5],  0.f) * w;
                h1.z = fmaxf(acc[i][6]  + bd[e*RANK+6],  0.f) * w;
                h1.w = fmaxf(acc[i][7]  + bd[e*RANK+7],  0.f) * w;
                h2.x = fmaxf(acc[i][8]  + bd[e*RANK+8],  0.f) * w;
                h2.y = fmaxf(acc[i][9]  + bd[e*RANK+9],  0.f) * w;
                h2.z = fmaxf(acc[i][10] + bd[e*RANK+10], 0.f) * w;
                h2.w = fmaxf(acc[i][11] + bd[e*RANK+11], 0.f) * w;
                h3.x = fmaxf(acc[i][12] + bd[e*RANK+12], 0.f) * w;
                h3.y = fmaxf(acc[i][13] + bd[e*RANK+13], 0.f) * w;
                h3.z = fmaxf(acc[i][14] + bd[e*RANK+14], 0.f) * w;
                h3.w = fmaxf(acc[i][15] + bd[e*RANK+15], 0.f) * w;
                float* hp = &hw[(size_t)t*32 + k*16];
                *(float4*)&hp[0]  = h0;
                *(float4*)&hp[4]  = h1;
                *(float4*)&hp[8]  = h2;
                *(float4*)&hp[12] = h3;
            }
        }
    }
}

// ---------------- K3: up projection: out[t][d] = sum_kr hw[t][kr]*Wu + w.bu ----------------
__global__ __launch_bounds__(256, 2)
void up_kernel(const float* __restrict__ Wu,
               const float* __restrict__ bu,
               const float2* __restrict__ wparams,
               const int* __restrict__ cnt,
               const int* __restrict__ to32,
               const unsigned short* __restrict__ lists,
               const float* __restrict__ hw,
               float* __restrict__ out,
               int nTok)
{
    const int bx = blockIdx.x;
    if (bx >= to32[NPAIR]) return;
    int p = 0;
    while (to32[p+1] <= bx) ++p;
    const int tile = bx - to32[p];
    const int m = min(32, cnt[p] - tile*32);
    int lo = 0, rem = p;
    while (rem >= (NEXP-1-lo)) { rem -= (NEXP-1-lo); ++lo; }
    const int hi = lo + 1 + rem;
    const int cc = blockIdx.y;        // d-chunk of 256

    __shared__ float wu_lds[2][16][256];   // 32 KB
    __shared__ float h_lds[32][36];        // 4.6 KB
    __shared__ float w2_lds[2][32];
    __shared__ int   tok_lds[32];

    const int tid = threadIdx.x;

    if (tid < 32) {
        const int idx = tile*32 + ((tid < m) ? tid : 0);
        const int t = lists[(size_t)p*nTok + idx];
        tok_lds[tid] = t;
        const float2 w = wparams[t];
        w2_lds[0][tid] = (tid < m) ? w.x : 0.f;
        w2_lds[1][tid] = (tid < m) ? w.y : 0.f;
    }

    // stage Wu chunk: direct global->LDS (no register staging array)
    #pragma unroll
    for (int i = 0; i < 8; ++i) {
        const int f  = i*1024 + tid*4;   // 0..8191
        const int kk = f >> 12;
        const int rr = (f >> 8) & 15;
        const int dd = f & 255;
        const int es = kk ? hi : lo;
        *(float4*)&wu_lds[kk][rr][dd] =
            *(const float4*)&Wu[(size_t)es*(RANK*DMODEL) + (size_t)rr*DMODEL + cc*256 + dd];
    }
    __syncthreads();

    {   // gather h' (1 float4 per thread; needs tok_lds)
        const int tk = tid >> 3, o = (tid & 7) * 4;
        const float4 hv = *(const float4*)&hw[(size_t)tok_lds[tk]*32 + o];
        *(float4*)&h_lds[tk][o] = hv;
    }
    __syncthreads();

    const int dg = tid & 31;    // 32 d-groups (4 floats each, two halves)
    const int tq = tid >> 5;    // 8 token quads
    float4 a0[4], a1[4];
    #pragma unroll
    for (int i = 0; i < 4; ++i) { a0[i] = make_float4(0,0,0,0); a1[i] = make_float4(0,0,0,0); }

    #pragma unroll 8
    for (int kr = 0; kr < 32; ++kr) {
        const int kk = kr >> 4, rr = kr & 15;
        const float4 u0 = *(const float4*)&wu_lds[kk][rr][dg*4];
        const float4 u1 = *(const float4*)&wu_lds[kk][rr][128 + dg*4];
        #pragma unroll
        for (int i = 0; i < 4; ++i) {
            const float hv = h_lds[tq*4 + i][kr];
            a0[i].x = fmaf(hv, u0.x, a0[i].x);
            a0[i].y = fmaf(hv, u0.y, a0[i].y);
            a0[i].z = fmaf(hv, u0.z, a0[i].z);
            a0[i].w = fmaf(hv, u0.w, a0[i].w);
            a1[i].x = fmaf(hv, u1.x, a1[i].x);
            a1[i].y = fmaf(hv, u1.y, a1[i].y);
            a1[i].z = fmaf(hv, u1.z, a1[i].z);
            a1[i].w = fmaf(hv, u1.w, a1[i].w);
        }
    }

    const float4 bl0 = *(const float4*)&bu[(size_t)lo*DMODEL + cc*256 + dg*4];
    const float4 bl1 = *(const float4*)&bu[(size_t)lo*DMODEL + cc*256 + 128 + dg*4];
    const float4 bh0 = *(const float4*)&bu[(size_t)hi*DMODEL + cc*256 + dg*4];
    const float4 bh1 = *(const float4*)&bu[(size_t)hi*DMODEL + cc*256 + 128 + dg*4];

    #pragma unroll
    for (int i = 0; i < 4; ++i) {
        const int slot = tq*4 + i;
        if (slot < m) {
            const int t = tok_lds[slot];
            const float wl = w2_lds[0][slot];
            const float wh = w2_lds[1][slot];
            float4 o0 = a0[i], o1 = a1[i];
            o0.x += wl*bl0.x + wh*bh0.x;  o0.y += wl*bl0.y + wh*bh0.y;
            o0.z += wl*bl0.z + wh*bh0.z;  o0.w += wl*bl0.w + wh*bh0.w;
            o1.x += wl*bl1.x + wh*bh1.x;  o1.y += wl*bl1.y + wh*bh1.y;
            o1.z += wl*bl1.z + wh*bh1.z;  o1.w += wl*bl1.w + wh*bh1.w;
            float* op = &out[(size_t)t*DMODEL + cc*256];
            *(float4*)&op[dg*4]       = o0;
            *(float4*)&op[128 + dg*4] = o1;
        }
    }
}

extern "C" void kernel_launch(void* const* d_in, const int* in_sizes, int n_in,
                              void* d_out, int out_size, void* d_ws, size_t ws_size,
                              hipStream_t stream)
{
    (void)n_in; (void)out_size; (void)ws_size;
    const float* x  = (const float*)d_in[0];
    const float* Wr = (const float*)d_in[1];
    const float* br = (const float*)d_in[2];
    const float* Wd = (const float*)d_in[3];
    const float* bd = (const float*)d_in[4];
    const float* Wu = (const float*)d_in[5];
    const float* bu = (const float*)d_in[6];
    float* out = (float*)d_out;
    const int nTok = in_sizes[0] / DMODEL;   // 8192

    char* base = (char*)d_ws;
    int* cnt  = (int*)(base);
    int* to16 = (int*)(base + 128);
    int* to32 = (int*)(base + 256);
    float2* wparams = (float2*)(base + 512);
    size_t off = 512 + (size_t)nTok*sizeof(float2);
    unsigned short* lists = (unsigned short*)(base + off);
    off += (size_t)NPAIR*nTok*sizeof(unsigned short);
    off = (off + 255) & ~(size_t)255;
    float* hw = (float*)(base + off);

    hipMemsetAsync(d_ws, 0, 512, stream);
    const int ntiles = (nTok + 31)/32;
    router_kernel<<<ntiles, 256, 0, stream>>>(x, Wr, br, wparams, cnt, lists, nTok);
    prefix_kernel<<<1, 64, 0, stream>>>(cnt, to16, to32);
    down_kernel<<<MAXT16, 256, 0, stream>>>(x, Wd, bd, wparams, cnt, to16, lists, hw, nTok);
    dim3 gup(MAXT32, 8);
    up_kernel<<<gup, 256, 0, stream>>>(Wu, bu, wparams, cnt, to32, lists, hw, out, nTok);
}